// Round 3
// baseline (9185.423 us; speedup 1.0000x reference)
//
#include <hip/hip_runtime.h>

#define NN   100000
#define DD   64
#define EE   3200000
#define GG   128
#define FF   1344
#define KK   60
#define RK   50
#define HIDN 32
#define NCL  696
#define BSPLIT 64

// 0: legacy split-iota halves; 1: partitionable hi word; 2: partitionable xor-fold; 3: partitionable lo word
#define OMEGA_VARIANT 2

// ---------------- threefry + erfinv (reproduce jax.random.normal(key(42), (F,60))) -------------
__device__ __forceinline__ unsigned rotl32(unsigned x, unsigned r){ return (x<<r)|(x>>(32u-r)); }

__device__ __forceinline__ void threefry(unsigned& x0, unsigned& x1){
  const unsigned ks0 = 0u, ks1 = 42u, ks2 = 0x1BD11BDAu ^ 0u ^ 42u;
  unsigned ks[3] = {ks0, ks1, ks2};
  const unsigned rotA[4] = {13u,15u,26u,6u};
  const unsigned rotB[4] = {17u,29u,16u,24u};
  x0 += ks0; x1 += ks1;
  #pragma unroll
  for (int i = 0; i < 5; ++i){
    #pragma unroll
    for (int j = 0; j < 4; ++j){
      unsigned r = (i & 1) ? rotB[j] : rotA[j];
      x0 += x1; x1 = rotl32(x1, r); x1 ^= x0;
    }
    x0 += ks[(i+1)%3]; x1 += ks[(i+2)%3] + (unsigned)(i+1);
  }
}

__device__ __forceinline__ float bits_to_normal(unsigned bits){
  unsigned mant = bits >> 9;
  float f; { unsigned fb = 0x3f800000u | mant; f = __uint_as_float(fb); }
  f -= 1.0f;                       // [0,1)
  const float lo = -0.99999994f;   // nextafter(-1,0)
  float u = fmaf(f, 2.0f, lo);     // (hi-lo) rounds to 2.0f; *2 exact so == mul+add
  u = fmaxf(lo, u);
  float w = -log1pf(-u*u);
  float p;
  if (w < 5.0f){
    w -= 2.5f;
    p = 2.81022636e-08f;
    p = fmaf(p, w, 3.43273939e-07f);
    p = fmaf(p, w, -3.5233877e-06f);
    p = fmaf(p, w, -4.39150654e-06f);
    p = fmaf(p, w, 0.00021858087f);
    p = fmaf(p, w, -0.00125372503f);
    p = fmaf(p, w, -0.00417768164f);
    p = fmaf(p, w, 0.246640727f);
    p = fmaf(p, w, 1.50140941f);
  } else {
    w = sqrtf(w) - 3.0f;
    p = -0.000200214257f;
    p = fmaf(p, w, 0.000100950558f);
    p = fmaf(p, w, 0.00134934322f);
    p = fmaf(p, w, -0.00367342844f);
    p = fmaf(p, w, 0.00573950773f);
    p = fmaf(p, w, -0.0076224613f);
    p = fmaf(p, w, 0.00943887047f);
    p = fmaf(p, w, 1.00167406f);
    p = fmaf(p, w, 2.83297682f);
  }
  return 1.41421356f * (p * u);
}

__global__ void k_omega(float* __restrict__ om){
  int i = blockIdx.x*blockDim.x + threadIdx.x;
#if OMEGA_VARIANT == 0
  const int half = (FF*KK)/2;
  if (i >= half) return;
  unsigned x0 = (unsigned)i, x1 = (unsigned)(i + half);
  threefry(x0, x1);
  om[i]        = bits_to_normal(x0);
  om[i + half] = bits_to_normal(x1);
#else
  if (i >= FF*KK) return;
  unsigned x0 = 0u, x1 = (unsigned)i;
  threefry(x0, x1);
#if OMEGA_VARIANT == 1
  om[i] = bits_to_normal(x0);
#elif OMEGA_VARIANT == 2
  om[i] = bits_to_normal(x0 ^ x1);
#else
  om[i] = bits_to_normal(x1);
#endif
#endif
}

// ---------------- CSR build ----------------
__global__ void k_count(const int* __restrict__ rows, int* __restrict__ cnt){
  int e = blockIdx.x*blockDim.x + threadIdx.x;
  if (e < EE) atomicAdd(&cnt[rows[e]], 1);
}

__global__ __launch_bounds__(1024) void k_scan1(const int* __restrict__ cnt,
    int* __restrict__ incl, int* __restrict__ bsums){
  __shared__ int buf[1024];
  int i = blockIdx.x*1024 + threadIdx.x;
  int v = (i < NN) ? cnt[i] : 0;
  buf[threadIdx.x] = v; __syncthreads();
  for (int ofs = 1; ofs < 1024; ofs <<= 1){
    int add = (threadIdx.x >= (unsigned)ofs) ? buf[threadIdx.x - ofs] : 0;
    __syncthreads();
    buf[threadIdx.x] += add;
    __syncthreads();
  }
  if (i < NN) incl[i] = buf[threadIdx.x];
  if (threadIdx.x == 1023) bsums[blockIdx.x] = buf[1023];
}

__global__ void k_scan2(int* __restrict__ bsums, int nb){
  if (threadIdx.x == 0){
    int run = 0;
    for (int i = 0; i < nb; ++i){ int v = bsums[i]; bsums[i] = run; run += v; }
  }
}

__global__ void k_scan3(const int* __restrict__ cnt, const int* __restrict__ bsums,
                        int* __restrict__ rowptr){
  int i = blockIdx.x*blockDim.x + threadIdx.x;
  if (i >= NN) return;
  int incl = rowptr[i];
  int ex = incl - cnt[i] + bsums[i >> 10];
  rowptr[i] = ex;
  if (i == NN-1) rowptr[NN] = ex + cnt[i];
}

__global__ void k_scatter(const int* __restrict__ rows, const int* __restrict__ cols,
                          const int* __restrict__ rowptr, int* __restrict__ tmpc,
                          int* __restrict__ csr){
  int e = blockIdx.x*blockDim.x + threadIdx.x;
  if (e >= EE) return;
  int r = rows[e];
  int p = atomicAdd(&tmpc[r], 1);
  csr[rowptr[r] + p] = cols[e];
}

__global__ void k_degr(const int* __restrict__ cnt, float* __restrict__ r1, float* __restrict__ r2){
  int i = blockIdx.x*blockDim.x + threadIdx.x;
  if (i >= NN) return;
  int d = cnt[i];
  float fd = (float)d;
  r1[i] = (d > 0) ? 1.0f/fd : 1.0f;
  r2[i] = 1.0f/(fd + 1e-5f);
}

// ---------------- propagation: base tensors ----------------
__global__ __launch_bounds__(256) void k_hop1(const float* __restrict__ x,
    const int* __restrict__ rp, const int* __restrict__ cc, float* __restrict__ ax){
  int n = blockIdx.x*4 + (threadIdx.x >> 6);
  int lane = threadIdx.x & 63;
  if (n >= NN) return;
  int s = rp[n], e = rp[n+1];
  float acc = 0.f;
  for (int idx = s; idx < e; ++idx){
    int c = cc[idx];
    acc += x[(size_t)c*64 + lane];
  }
  ax[(size_t)n*64 + lane] = acc;
}

__global__ __launch_bounds__(256) void k_hop2(const int* __restrict__ rp, const int* __restrict__ cc,
    const float* __restrict__ ax, const float* __restrict__ r1, const float* __restrict__ r2,
    float* __restrict__ S0, float* __restrict__ S1, float* __restrict__ S3){
  int n = blockIdx.x*4 + (threadIdx.x >> 6);
  int lane = threadIdx.x & 63;
  if (n >= NN) return;
  int s = rp[n], e = rp[n+1];
  float s0 = 0.f, s1 = 0.f, s3 = 0.f;
  for (int idx = s; idx < e; ++idx){
    int c = cc[idx];
    float v   = ax[(size_t)c*64 + lane];
    float rc1 = r1[c], rc2 = r2[c];
    s0 += v;
    s1 = fmaf(v, rc1, s1);
    s3 = fmaf(v, rc2, s3);
  }
  S0[(size_t)n*64 + lane] = s0;
  S1[(size_t)n*64 + lane] = s1;
  S3[(size_t)n*64 + lane] = s3;
}

// ---------------- Beff build: Beff[20][64][60] from B[F x 60] ----------------
__global__ void k_beff(const float* __restrict__ B, float* __restrict__ Beff){
  int gid = blockIdx.x*blockDim.x + threadIdx.x;
  if (gid >= 20*3840) return;
  int p = gid / 3840;
  int rem = gid - p*3840;
  int r = rem / 60, k = rem - (rem/60)*60;
  int t = p >> 2, j = p & 3;
  float val = 0.f;
  if (t == 0)      val = (j == 0) ? B[(0*64 + r)*60 + k] : 0.f;
  else if (t == 1) val = B[((1+j)*64 + r)*60 + k];
  else if (t == 2) val = B[((5+j)*64 + r)*60 + k] + 1.5e-6f*B[((13+j)*64 + r)*60 + k];
  else if (t == 3) val = B[((9+j)*64 + r)*60 + k] + 0.85f  *B[((13+j)*64 + r)*60 + k];
  else             val = B[((17+j)*64 + r)*60 + k];
  Beff[gid] = val;
}

// ---------------- forward: Y[N x 60] = sum_p c_p ∘ (T_p @ Beff_p) ----------------
__global__ __launch_bounds__(256) void k_fwd(
    const float* __restrict__ xi, const float* __restrict__ ax,
    const float* __restrict__ S0, const float* __restrict__ S1,
    const float* __restrict__ S3, const float* __restrict__ Beff,
    const float* __restrict__ r1, const float* __restrict__ r2,
    float* __restrict__ Y){
  __shared__ float As[64][76];
  __shared__ float Bs[64][64];
  __shared__ float cS[4][64];
  const float* Ts[5] = {xi, ax, S0, S1, S3};
  const int pcnt[5] = {1,4,4,4,4};
  int n0 = blockIdx.x*64;
  int tid = threadIdx.x;
  int tx = tid & 15, ty = tid >> 4;
  if (tid < 64){
    int gn = n0 + tid;
    float r1v = 0.f, r2v = 0.f, one = 0.f;
    if (gn < NN){ r1v = r1[gn]; r2v = r2[gn]; one = 1.f; }
    cS[0][tid] = one;
    cS[1][tid] = r1v;
    cS[2][tid] = fmaf(0.85f, r1v, 1.5e-6f*one);
    cS[3][tid] = r2v;
  }
  float acc[4][4] = {};
  for (int t = 0; t < 5; ++t){
    __syncthreads();
    const float* T = Ts[t];
    #pragma unroll
    for (int l = 0; l < 4; ++l){
      int li = tid + l*256;
      int n = li >> 4, fq = (li & 15)*4;
      int gn = n0 + n;
      float4 v = make_float4(0.f,0.f,0.f,0.f);
      if (gn < NN) v = *(const float4*)(T + (size_t)gn*64 + fq);
      *(float4*)&As[n][fq] = v;
    }
    for (int jj = 0; jj < pcnt[t]; ++jj){
      int p = t*4 + jj;
      __syncthreads();
      for (int idx = tid; idx < 64*64; idx += 256){
        int r = idx >> 6, c = idx & 63;
        Bs[r][c] = (c < KK) ? Beff[(size_t)p*3840 + r*60 + c] : 0.f;
      }
      __syncthreads();
      float ptmp[4][4] = {};
      for (int kk = 0; kk < 64; ++kk){
        float a0 = As[ty*4+0][kk];
        float a1 = As[ty*4+1][kk];
        float a2 = As[ty*4+2][kk];
        float a3 = As[ty*4+3][kk];
        float4 b = *(const float4*)&Bs[kk][tx*4];
        ptmp[0][0]=fmaf(a0,b.x,ptmp[0][0]); ptmp[0][1]=fmaf(a0,b.y,ptmp[0][1]);
        ptmp[0][2]=fmaf(a0,b.z,ptmp[0][2]); ptmp[0][3]=fmaf(a0,b.w,ptmp[0][3]);
        ptmp[1][0]=fmaf(a1,b.x,ptmp[1][0]); ptmp[1][1]=fmaf(a1,b.y,ptmp[1][1]);
        ptmp[1][2]=fmaf(a1,b.z,ptmp[1][2]); ptmp[1][3]=fmaf(a1,b.w,ptmp[1][3]);
        ptmp[2][0]=fmaf(a2,b.x,ptmp[2][0]); ptmp[2][1]=fmaf(a2,b.y,ptmp[2][1]);
        ptmp[2][2]=fmaf(a2,b.z,ptmp[2][2]); ptmp[2][3]=fmaf(a2,b.w,ptmp[2][3]);
        ptmp[3][0]=fmaf(a3,b.x,ptmp[3][0]); ptmp[3][1]=fmaf(a3,b.y,ptmp[3][1]);
        ptmp[3][2]=fmaf(a3,b.z,ptmp[3][2]); ptmp[3][3]=fmaf(a3,b.w,ptmp[3][3]);
      }
      #pragma unroll
      for (int i = 0; i < 4; ++i){
        float cv = cS[jj][ty*4+i];
        #pragma unroll
        for (int q = 0; q < 4; ++q) acc[i][q] = fmaf(cv, ptmp[i][q], acc[i][q]);
      }
    }
  }
  #pragma unroll
  for (int i = 0; i < 4; ++i){
    int gn = n0 + ty*4 + i;
    if (gn >= NN) continue;
    #pragma unroll
    for (int q = 0; q < 4; ++q){
      int c = tx*4 + q;
      if (c < KK) Y[(size_t)gn*KK + c] = acc[i][q];
    }
  }
}

// ---------------- backward partials: P(t,j) = T_t^T (c_j ∘ Q), split over N ----------------
__device__ __forceinline__ void fma44(const float4 a, const float4 b, float (&acc)[4][4]){
  acc[0][0] = fmaf(a.x,b.x,acc[0][0]); acc[0][1] = fmaf(a.x,b.y,acc[0][1]);
  acc[0][2] = fmaf(a.x,b.z,acc[0][2]); acc[0][3] = fmaf(a.x,b.w,acc[0][3]);
  acc[1][0] = fmaf(a.y,b.x,acc[1][0]); acc[1][1] = fmaf(a.y,b.y,acc[1][1]);
  acc[1][2] = fmaf(a.y,b.z,acc[1][2]); acc[1][3] = fmaf(a.y,b.w,acc[1][3]);
  acc[2][0] = fmaf(a.z,b.x,acc[2][0]); acc[2][1] = fmaf(a.z,b.y,acc[2][1]);
  acc[2][2] = fmaf(a.z,b.z,acc[2][2]); acc[2][3] = fmaf(a.z,b.w,acc[2][3]);
  acc[3][0] = fmaf(a.w,b.x,acc[3][0]); acc[3][1] = fmaf(a.w,b.y,acc[3][1]);
  acc[3][2] = fmaf(a.w,b.z,acc[3][2]); acc[3][3] = fmaf(a.w,b.w,acc[3][3]);
}

__global__ __launch_bounds__(256) void k_bwd(
    const float* __restrict__ xi, const float* __restrict__ ax,
    const float* __restrict__ S0t, const float* __restrict__ S1t,
    const float* __restrict__ S3t, const float* __restrict__ Qm,
    const float* __restrict__ r1, const float* __restrict__ r2,
    float* __restrict__ Ppart){
  const float* T = (blockIdx.x==0)?xi:(blockIdx.x==1)?ax:(blockIdx.x==2)?S0t:(blockIdx.x==3)?S1t:S3t;
  const int TT = (NN + 15)/16;
  int per = (TT + BSPLIT - 1)/BSPLIT;
  int t0 = blockIdx.y * per;
  int t1 = t0 + per; if (t1 > TT) t1 = TT;
  __shared__ float Hs[16][68];
  __shared__ float Qs[16][64];
  __shared__ float cs[4][16];
  int tid = threadIdx.x, tx = tid & 15, ty = tid >> 4;
  float acc[4][4][4] = {};
  for (int tl = t0; tl < t1; ++tl){
    int nb = tl*16;
    {
      int n = tid >> 4, fq = (tid & 15)*4;
      int gn = nb + n;
      float4 v = make_float4(0.f,0.f,0.f,0.f);
      if (gn < NN) v = *(const float4*)(T + (size_t)gn*64 + fq);
      *(float4*)&Hs[n][fq] = v;
    }
    if (tid < 240){
      int n = tid/15, cq = (tid - (tid/15)*15)*4;
      int gn = nb + n;
      float4 v = make_float4(0.f,0.f,0.f,0.f);
      if (gn < NN) v = *(const float4*)(Qm + (size_t)gn*KK + cq);
      *(float4*)&Qs[n][cq] = v;
    } else {
      int n = tid - 240;
      Qs[n][60]=0.f; Qs[n][61]=0.f; Qs[n][62]=0.f; Qs[n][63]=0.f;
    }
    if (tid < 64){
      int j = tid >> 4, n = tid & 15;
      int gn = nb + n;
      float r1v = 0.f, r2v = 0.f, one = 0.f;
      if (gn < NN){ r1v = r1[gn]; r2v = r2[gn]; one = 1.f; }
      cs[j][n] = (j==0) ? one : (j==1) ? r1v : (j==2) ? fmaf(0.85f, r1v, 1.5e-6f*one) : r2v;
    }
    __syncthreads();
    #pragma unroll 4
    for (int n = 0; n < 16; ++n){
      float4 a = *(const float4*)&Hs[n][tx*4];
      float4 b = *(const float4*)&Qs[n][ty*4];
      #pragma unroll
      for (int j = 0; j < 4; ++j){
        float cj = cs[j][n];
        float4 bj = make_float4(b.x*cj, b.y*cj, b.z*cj, b.w*cj);
        fma44(a, bj, acc[j]);
      }
    }
    __syncthreads();
  }
  float* dst = Ppart + (size_t)blockIdx.y * 76800;
  #pragma unroll
  for (int j = 0; j < 4; ++j){
    #pragma unroll
    for (int i = 0; i < 4; ++i){
      int f = tx*4 + i;
      #pragma unroll
      for (int q = 0; q < 4; ++q){
        int k = ty*4 + q;
        if (k < KK) dst[(size_t)((blockIdx.x*4 + j)*64 + f)*60 + k] = acc[j][i][q];
      }
    }
  }
}

__global__ void k_pred(const float* __restrict__ Ppart, float* __restrict__ P){
  int gid = blockIdx.x*blockDim.x + threadIdx.x;
  if (gid >= 20*3840) return;
  float s = 0.f;
  for (int b = 0; b < BSPLIT; ++b) s += Ppart[(size_t)b*76800 + gid];
  P[gid] = s;
}

// Z[F x 60] assembled from P[5][4][64][60]
__global__ void k_zasm(const float* __restrict__ P, float* __restrict__ Z){
  int gid = blockIdx.x*blockDim.x + threadIdx.x;
  if (gid >= FF*KK) return;
  int f = gid / 60, k = gid - (gid/60)*60;
  int b = f >> 6, fi = f & 63;
  float val;
  if (b == 0)       val = P[(size_t)((0*4+0)*64 + fi)*60 + k];
  else if (b < 5)   val = P[(size_t)((1*4 + (b-1))*64 + fi)*60 + k];
  else if (b < 9)   val = P[(size_t)((2*4 + (b-5))*64 + fi)*60 + k];
  else if (b < 13)  val = P[(size_t)((3*4 + (b-9))*64 + fi)*60 + k];
  else if (b < 17)  val = 0.85f  *P[(size_t)((3*4 + (b-13))*64 + fi)*60 + k]
                        + 1.5e-6f*P[(size_t)((2*4 + (b-13))*64 + fi)*60 + k];
  else              val = P[(size_t)((4*4 + (b-17))*64 + fi)*60 + k];
  Z[gid] = val;
}

// ---------------- CholQR pieces ----------------
__global__ __launch_bounds__(256) void k_syrk(const float* __restrict__ X, int nrows,
                                              float* __restrict__ Cout){
  int chunk = (nrows + gridDim.x - 1) / gridDim.x;
  int nb = blockIdx.x * chunk;
  int ne = nb + chunk; if (ne > nrows) ne = nrows;
  __shared__ float Xs[16][64];
  int tid = threadIdx.x;
  int tx = tid & 15, ty = tid >> 4;
  float acc[4][4] = {};
  for (int nbase = nb; nbase < ne; nbase += 16){
    if (tid < 240){
      int n = tid / 15, ci = tid - (tid/15)*15;
      float4 v = make_float4(0.f,0.f,0.f,0.f);
      int gn = nbase + n;
      if (gn < ne) v = *(const float4*)(X + (size_t)gn*KK + ci*4);
      *(float4*)&Xs[n][ci*4] = v;
    } else {
      int n = tid - 240;
      Xs[n][60]=0.f; Xs[n][61]=0.f; Xs[n][62]=0.f; Xs[n][63]=0.f;
    }
    __syncthreads();
    #pragma unroll
    for (int n = 0; n < 16; ++n){
      float4 a = *(const float4*)&Xs[n][tx*4];
      float4 b = *(const float4*)&Xs[n][ty*4];
      fma44(a, b, acc);
    }
    __syncthreads();
  }
  #pragma unroll
  for (int i = 0; i < 4; ++i){
    int r = tx*4 + i;
    #pragma unroll
    for (int j = 0; j < 4; ++j){
      int c = ty*4 + j;
      if (r < KK && c < KK) atomicAdd(&Cout[r*KK + c], acc[i][j]);
    }
  }
}

__global__ void k_cholinv(const float* __restrict__ Cin, float* __restrict__ Rinv){
  __shared__ float R[60][61];
  __shared__ float Ri[60][61];
  __shared__ float ridge;
  int t = threadIdx.x;
  for (int i = t; i < 3600; i += 64) R[i/60][i%60] = Cin[i];
  __syncthreads();
  if (t == 0){
    float tr = 0.f;
    for (int i = 0; i < 60; ++i) tr += R[i][i];
    ridge = 1e-7f*(tr/60.f) + 1e-30f;
  }
  __syncthreads();
  if (t < 60) R[t][t] += ridge;
  __syncthreads();
  for (int j = 0; j < 60; ++j){
    if (t == 0){ float d = R[j][j]; d = fmaxf(d, 1e-30f); R[j][j] = sqrtf(d); }
    __syncthreads();
    float rjj = R[j][j];
    for (int i = j+1+t; i < 60; i += 64) R[j][i] /= rjj;
    __syncthreads();
    int total = (59-j)*60;
    for (int idx = t; idx < total; idx += 64){
      int k = j + 1 + idx/60, i = idx%60;
      if (i >= k) R[k][i] -= R[j][k]*R[j][i];
    }
    __syncthreads();
  }
  for (int i = t; i < 3600; i += 64) Ri[i/60][i%60] = 0.f;
  __syncthreads();
  if (t < 60){
    int c = t;
    Ri[c][c] = 1.0f / R[c][c];
    for (int i = c-1; i >= 0; --i){
      float s = 0.f;
      for (int k = i+1; k <= c; ++k) s += R[i][k]*Ri[k][c];
      Ri[i][c] = -s / R[i][i];
    }
  }
  __syncthreads();
  for (int i = t; i < 3600; i += 64) Rinv[i] = Ri[i/60][i%60];
}

// X = Y @ Rinv — safe in-place (each row owned by one wave)
__global__ __launch_bounds__(256) void k_applyR(const float* Yin,
    const float* __restrict__ Rinv, float* Xout, int nrows){
  __shared__ float Rs[3664];
  for (int i = threadIdx.x; i < 3664; i += 256) Rs[i] = (i < 3600) ? Rinv[i] : 0.f;
  __syncthreads();
  int n = blockIdx.x*4 + (threadIdx.x >> 6);
  int lane = threadIdx.x & 63;
  if (n >= nrows) return;
  const float* y = Yin + (size_t)n*KK;
  float accv = 0.f;
  #pragma unroll 10
  for (int k2 = 0; k2 < KK; ++k2) accv = fmaf(y[k2], Rs[k2*KK + lane], accv);
  if (lane < KK) Xout[(size_t)n*KK + lane] = accv;
}

// WB[60x64] = Z^T @ w
__global__ void k_wb(const float* __restrict__ Z, const float* __restrict__ w,
                     float* __restrict__ WB){
  int gid = blockIdx.x*blockDim.x + threadIdx.x;
  if (gid >= KK*64) return;
  int r = gid >> 6, d = gid & 63;
  float acc = 0.f;
  for (int f = 0; f < FF; ++f) acc = fmaf(Z[(size_t)f*KK + r], w[(size_t)f*64 + d], acc);
  WB[gid] = acc;
}

// Jacobi eigensolver on 60x60; top-50 eigvecs
__global__ __launch_bounds__(256) void k_jacobi(const float* __restrict__ Min,
                                                float* __restrict__ U50){
  __shared__ float A[60][61];
  __shared__ float Vv[60][61];
  __shared__ float cs[30], sn[30];
  __shared__ int pp[30], qq[30];
  __shared__ float ev[60];
  __shared__ int idx[60];
  int t = threadIdx.x;
  for (int i = t; i < 3600; i += 256) A[i/60][i%60] = Min[i];
  for (int i = t; i < 3600; i += 256) Vv[i/60][i%60] = (i/60 == i%60) ? 1.f : 0.f;
  __syncthreads();
  for (int sweep = 0; sweep < 8; ++sweep){
    for (int round = 0; round < 59; ++round){
      if (t < 30){
        int i = t, j2 = 59 - t;
        int p = (i == 0) ? 0 : ((i - 1 + round) % 59 + 1);
        int q = ((j2 - 1 + round) % 59 + 1);
        if (p > q){ int tv = p; p = q; q = tv; }
        pp[t] = p; qq[t] = q;
        float app = A[p][p], aqq = A[q][q], apq = A[p][q];
        float c, s;
        if (fabsf(apq) < 1e-36f){ c = 1.f; s = 0.f; }
        else {
          float tau = (aqq - app) / (2.f * apq);
          float tt = ((tau >= 0.f) ? 1.f : -1.f) / (fabsf(tau) + sqrtf(1.f + tau*tau));
          c = 1.f / sqrtf(1.f + tt*tt);
          s = tt * c;
        }
        cs[t] = c; sn[t] = s;
      }
      __syncthreads();
      for (int task = t; task < 1800; task += 256){
        int k = task / 60, i = task % 60;
        int p = pp[k], q = qq[k];
        float c = cs[k], s = sn[k];
        float aip = A[i][p], aiq = A[i][q];
        A[i][p] = c*aip - s*aiq;  A[i][q] = s*aip + c*aiq;
        float vip = Vv[i][p], viq = Vv[i][q];
        Vv[i][p] = c*vip - s*viq; Vv[i][q] = s*vip + c*viq;
      }
      __syncthreads();
      for (int task = t; task < 1800; task += 256){
        int k = task / 60, i = task % 60;
        int p = pp[k], q = qq[k];
        float c = cs[k], s = sn[k];
        float api = A[p][i], aqi = A[q][i];
        A[p][i] = c*api - s*aqi;  A[q][i] = s*api + c*aqi;
      }
      __syncthreads();
    }
  }
  if (t == 0){
    for (int i = 0; i < 60; ++i){ ev[i] = A[i][i]; idx[i] = i; }
    for (int a = 0; a < 50; ++a){
      int best = a;
      for (int b2 = a+1; b2 < 60; ++b2) if (ev[idx[b2]] > ev[idx[best]]) best = b2;
      int tv = idx[a]; idx[a] = idx[best]; idx[best] = tv;
    }
  }
  __syncthreads();
  for (int i2 = t; i2 < 60*RK; i2 += 256){
    int r = i2 / RK, c = i2 % RK;
    U50[i2] = Vv[r][idx[c]];
  }
}

__global__ void k_g50(const float* __restrict__ U50, const float* __restrict__ WB,
                      float* __restrict__ G50){
  int gid = blockIdx.x*blockDim.x + threadIdx.x;
  if (gid >= RK*64) return;
  int r = gid >> 6, d = gid & 63;
  float acc = 0.f;
  for (int i = 0; i < KK; ++i) acc = fmaf(U50[i*RK + r], WB[i*64 + d], acc);
  G50[gid] = acc;
}

__global__ void k_T(const float* __restrict__ U50, const float* __restrict__ G50,
                    float* __restrict__ Tm){
  int gid = blockIdx.x*blockDim.x + threadIdx.x;
  if (gid >= KK*64) return;
  int i = gid >> 6, d = gid & 63;
  float acc = 0.f;
  for (int r = 0; r < RK; ++r) acc = fmaf(U50[i*RK + r], G50[r*64 + d], acc);
  Tm[gid] = acc;
}

__global__ void k_TW1(const float* __restrict__ Tm, const float* __restrict__ W1,
                      float* __restrict__ TW1){
  int gid = blockIdx.x*blockDim.x + threadIdx.x;
  if (gid >= KK*HIDN) return;
  int i = gid >> 5, j = gid & 31;
  float acc = 0.f;
  for (int d = 0; d < 64; ++d) acc = fmaf(Tm[i*64 + d], W1[d*HIDN + j], acc);
  TW1[gid] = acc;
}

__global__ __launch_bounds__(256) void k_hid(const float* __restrict__ Q,
    const float* __restrict__ TW1, const float* __restrict__ b1, float* __restrict__ hid){
  __shared__ float Ts[KK*HIDN];
  __shared__ float bs[HIDN];
  for (int i = threadIdx.x; i < KK*HIDN; i += 256) Ts[i] = TW1[i];
  if (threadIdx.x < HIDN) bs[threadIdx.x] = b1[threadIdx.x];
  __syncthreads();
  int gid = blockIdx.x*256 + threadIdx.x;
  if (gid >= NN*HIDN) return;
  int n = gid >> 5, j = gid & 31;
  const float* q = Q + (size_t)n*KK;
  float a = bs[j];
  #pragma unroll 10
  for (int k2 = 0; k2 < KK; ++k2) a = fmaf(q[k2], Ts[k2*HIDN + j], a);
  hid[gid] = (a >= 0.f) ? a : 0.01f*a;
}

__global__ void k_gstart(const int* __restrict__ gids, int* __restrict__ gst){
  int g = blockIdx.x*blockDim.x + threadIdx.x;
  if (g > GG) return;
  if (g == GG){ gst[GG] = NN; return; }
  int lo = 0, hi = NN;
  while (lo < hi){ int mid = (lo + hi) >> 1; if (gids[mid] < g) lo = mid + 1; else hi = mid; }
  gst[g] = lo;
}

__global__ __launch_bounds__(256) void k_pool(const float* __restrict__ hid,
    const float* __restrict__ W2, const int* __restrict__ gst, float* __restrict__ out){
  int g = blockIdx.x, ct = blockIdx.y;
  int c0 = ct * 64;
  __shared__ float W2s[HIDN][64];
  __shared__ float part[4][64];
  for (int i = threadIdx.x; i < HIDN*64; i += 256){
    int k2 = i >> 6, c = i & 63;
    int col = c0 + c;
    W2s[k2][c] = (col < NCL) ? W2[(size_t)k2*NCL + col] : 0.f;
  }
  __syncthreads();
  int w = threadIdx.x >> 6, lane = threadIdx.x & 63;
  int s = gst[g], e = gst[g+1];
  float accv = 0.f;
  for (int n = s + w; n < e; n += 4){
    const float* hr = hid + (size_t)n*HIDN;
    #pragma unroll
    for (int k2 = 0; k2 < HIDN; ++k2) accv = fmaf(hr[k2], W2s[k2][lane], accv);
  }
  part[w][lane] = accv;
  __syncthreads();
  if (w == 0){
    float v = part[0][lane] + part[1][lane] + part[2][lane] + part[3][lane];
    int col = c0 + lane;
    if (col < NCL) out[(size_t)g*NCL + col] = v;
  }
}

// ---------------- host ----------------
extern "C" void kernel_launch(void* const* d_in, const int* in_sizes, int n_in,
                              void* d_out, int out_size, void* d_ws, size_t ws_size,
                              hipStream_t stream){
  (void)in_sizes; (void)n_in; (void)out_size;
  const float* x   = (const float*)d_in[0];
  const int*  rows = (const int*)d_in[1];
  const int*  cols = (const int*)d_in[2];
  const int*  gids = (const int*)d_in[3];
  const float* wM  = (const float*)d_in[5];
  const float* W1  = (const float*)d_in[6];
  const float* b1  = (const float*)d_in[7];
  const float* W2  = (const float*)d_in[8];
  float* out = (float*)d_out;

  char* base = (char*)d_ws;
  size_t off = 0;
  auto alloc = [&](size_t bytes)->char*{
    off = (off + 255) & ~(size_t)255;
    char* p = base + off; off += bytes; return p;
  };
  float* ax    = (float*)alloc((size_t)NN*64*4);   // later reused as hid
  float* S0    = (float*)alloc((size_t)NN*64*4);
  float* S1    = (float*)alloc((size_t)NN*64*4);
  float* S3    = (float*)alloc((size_t)NN*64*4);
  float* Y     = (float*)alloc((size_t)NN*KK*4);   // becomes Q in place
  int*   csr   = (int*)  alloc((size_t)EE*4);
  float* Ppart = (float*)alloc((size_t)BSPLIT*20*3840*4);
  float* Psum  = (float*)alloc((size_t)20*3840*4);
  float* Beff  = (float*)alloc((size_t)20*3840*4);
  float* Om    = (float*)alloc((size_t)FF*KK*4);
  float* Zf    = (float*)alloc((size_t)FF*KK*4);
  float* Cm    = (float*)alloc(3600*4);
  float* Rinv  = (float*)alloc(3600*4);
  float* Mm    = (float*)alloc(3600*4);
  float* U50   = (float*)alloc(60*RK*4);
  float* WB    = (float*)alloc(KK*64*4);
  float* G50   = (float*)alloc(RK*64*4);
  float* Tm    = (float*)alloc(KK*64*4);
  float* TW1   = (float*)alloc(KK*HIDN*4);
  float* r1    = (float*)alloc((size_t)NN*4);
  float* r2    = (float*)alloc((size_t)NN*4);
  int* cnt     = (int*)alloc((size_t)NN*4);
  int* rowptr  = (int*)alloc((size_t)(NN+1)*4);
  int* tmpc    = (int*)alloc((size_t)NN*4);
  int* gst     = (int*)alloc((size_t)(GG+1)*4);
  int* bsums   = (int*)alloc(256*4);
  float* hid   = ax;  // overlay: ax dead after final k_bwd
  if (off > ws_size) return;

  const int SCAN_B = (NN + 1023) / 1024;

  // ---- graph prep ----
  hipMemsetAsync(cnt, 0, (size_t)NN*4, stream);
  k_count<<<(EE+255)/256, 256, 0, stream>>>(rows, cnt);
  k_scan1<<<SCAN_B, 1024, 0, stream>>>(cnt, rowptr, bsums);
  k_scan2<<<1, 64, 0, stream>>>(bsums, SCAN_B);
  k_scan3<<<(NN+255)/256, 256, 0, stream>>>(cnt, bsums, rowptr);
  hipMemsetAsync(tmpc, 0, (size_t)NN*4, stream);
  k_scatter<<<(EE+255)/256, 256, 0, stream>>>(rows, cols, rowptr, tmpc, csr);
  k_degr<<<(NN+255)/256, 256, 0, stream>>>(cnt, r1, r2);

  // ---- base tensors ----
  k_hop1<<<(NN+3)/4, 256, 0, stream>>>(x, rowptr, csr, ax);
  k_hop2<<<(NN+3)/4, 256, 0, stream>>>(rowptr, csr, ax, r1, r2, S0, S1, S3);

  // ---- omega ----
  k_omega<<<(FF*KK+255)/256, 256, 0, stream>>>(Om);

  auto cholqr = [&](float* Ybuf, int nrows, int syrkGrid){
    hipMemsetAsync(Cm, 0, 3600*4, stream);
    k_syrk<<<syrkGrid, 256, 0, stream>>>(Ybuf, nrows, Cm);
    k_cholinv<<<1, 64, 0, stream>>>(Cm, Rinv);
    k_applyR<<<(nrows+3)/4, 256, 0, stream>>>(Ybuf, Rinv, Ybuf, nrows);
  };
  auto bwd = [&](){
    k_bwd<<<dim3(5, BSPLIT), 256, 0, stream>>>(x, ax, S0, S1, S3, Y, r1, r2, Ppart);
    k_pred<<<(20*3840+255)/256, 256, 0, stream>>>(Ppart, Psum);
    k_zasm<<<(FF*KK+255)/256, 256, 0, stream>>>(Psum, Zf);
  };
  auto fwd = [&](const float* Bmat){
    k_beff<<<(20*3840+255)/256, 256, 0, stream>>>(Bmat, Beff);
    k_fwd<<<(NN+63)/64, 256, 0, stream>>>(x, ax, S0, S1, S3, Beff, r1, r2, Y);
  };

  // ---- Q0 = qr(h @ omega) ----
  fwd(Om);
  cholqr(Y, NN, 256);

  // ---- power iterations ----
  for (int it = 0; it < 4; ++it){
    bwd();
    cholqr(Zf, FF, 32);     // Zf becomes Qf in place
    fwd(Zf);
    cholqr(Y, NN, 256);
  }
  cholqr(Y, NN, 256);       // CholQR2: final Q orthonormal to ~eps

  // ---- B-side smalls ----
  bwd();                    // Zf = h^T Q
  hipMemsetAsync(Mm, 0, 3600*4, stream);
  k_syrk<<<32, 256, 0, stream>>>(Zf, FF, Mm);
  k_wb<<<(KK*64+255)/256, 256, 0, stream>>>(Zf, wM, WB);

  // ---- eigensolve + projector chain ----
  k_jacobi<<<1, 256, 0, stream>>>(Mm, U50);
  k_g50<<<(RK*64+255)/256, 256, 0, stream>>>(U50, WB, G50);
  k_T<<<(KK*64+255)/256, 256, 0, stream>>>(U50, G50, Tm);
  k_TW1<<<(KK*HIDN+255)/256, 256, 0, stream>>>(Tm, W1, TW1);

  // ---- MLP + pooling (hid overlays ax) ----
  k_hid<<<(NN*HIDN+255)/256, 256, 0, stream>>>(Y, TW1, b1, hid);
  k_gstart<<<1, 256, 0, stream>>>(gids, gst);
  k_pool<<<dim3(GG, (NCL+63)/64), 256, 0, stream>>>(hid, W2, gst, out);
}

// Round 4
// 6626.595 us; speedup vs baseline: 1.3861x; 1.3861x over previous
//
#include <hip/hip_runtime.h>

#define NN   100000
#define DD   64
#define EE   3200000
#define GG   128
#define FF   1344
#define KK   60
#define RK   50
#define HIDN 32
#define NCL  696
#define BSPLIT 128

#define OMEGA_VARIANT 2   // partitionable xor-fold: VERIFIED round 3 (absmax 32 < 149.76)

// ---------------- threefry + erfinv ----------------
__device__ __forceinline__ unsigned rotl32(unsigned x, unsigned r){ return (x<<r)|(x>>(32u-r)); }

__device__ __forceinline__ void threefry(unsigned& x0, unsigned& x1){
  const unsigned ks0 = 0u, ks1 = 42u, ks2 = 0x1BD11BDAu ^ 0u ^ 42u;
  unsigned ks[3] = {ks0, ks1, ks2};
  const unsigned rotA[4] = {13u,15u,26u,6u};
  const unsigned rotB[4] = {17u,29u,16u,24u};
  x0 += ks0; x1 += ks1;
  #pragma unroll
  for (int i = 0; i < 5; ++i){
    #pragma unroll
    for (int j = 0; j < 4; ++j){
      unsigned r = (i & 1) ? rotB[j] : rotA[j];
      x0 += x1; x1 = rotl32(x1, r); x1 ^= x0;
    }
    x0 += ks[(i+1)%3]; x1 += ks[(i+2)%3] + (unsigned)(i+1);
  }
}

__device__ __forceinline__ float bits_to_normal(unsigned bits){
  unsigned mant = bits >> 9;
  float f; { unsigned fb = 0x3f800000u | mant; f = __uint_as_float(fb); }
  f -= 1.0f;
  const float lo = -0.99999994f;
  float u = fmaf(f, 2.0f, lo);
  u = fmaxf(lo, u);
  float w = -log1pf(-u*u);
  float p;
  if (w < 5.0f){
    w -= 2.5f;
    p = 2.81022636e-08f;
    p = fmaf(p, w, 3.43273939e-07f);
    p = fmaf(p, w, -3.5233877e-06f);
    p = fmaf(p, w, -4.39150654e-06f);
    p = fmaf(p, w, 0.00021858087f);
    p = fmaf(p, w, -0.00125372503f);
    p = fmaf(p, w, -0.00417768164f);
    p = fmaf(p, w, 0.246640727f);
    p = fmaf(p, w, 1.50140941f);
  } else {
    w = sqrtf(w) - 3.0f;
    p = -0.000200214257f;
    p = fmaf(p, w, 0.000100950558f);
    p = fmaf(p, w, 0.00134934322f);
    p = fmaf(p, w, -0.00367342844f);
    p = fmaf(p, w, 0.00573950773f);
    p = fmaf(p, w, -0.0076224613f);
    p = fmaf(p, w, 0.00943887047f);
    p = fmaf(p, w, 1.00167406f);
    p = fmaf(p, w, 2.83297682f);
  }
  return 1.41421356f * (p * u);
}

__global__ void k_omega(float* __restrict__ om){
  int i = blockIdx.x*blockDim.x + threadIdx.x;
  if (i >= FF*KK) return;
  unsigned x0 = 0u, x1 = (unsigned)i;
  threefry(x0, x1);
  om[i] = bits_to_normal(x0 ^ x1);
}

// ---------------- CSR build ----------------
__global__ void k_count(const int* __restrict__ rows, int* __restrict__ cnt){
  int e = blockIdx.x*blockDim.x + threadIdx.x;
  if (e < EE) atomicAdd(&cnt[rows[e]], 1);
}

__global__ __launch_bounds__(1024) void k_scan1(const int* __restrict__ cnt,
    int* __restrict__ incl, int* __restrict__ bsums){
  __shared__ int buf[1024];
  int i = blockIdx.x*1024 + threadIdx.x;
  int v = (i < NN) ? cnt[i] : 0;
  buf[threadIdx.x] = v; __syncthreads();
  for (int ofs = 1; ofs < 1024; ofs <<= 1){
    int add = (threadIdx.x >= (unsigned)ofs) ? buf[threadIdx.x - ofs] : 0;
    __syncthreads();
    buf[threadIdx.x] += add;
    __syncthreads();
  }
  if (i < NN) incl[i] = buf[threadIdx.x];
  if (threadIdx.x == 1023) bsums[blockIdx.x] = buf[1023];
}

__global__ void k_scan2(int* __restrict__ bsums, int nb){
  if (threadIdx.x == 0){
    int run = 0;
    for (int i = 0; i < nb; ++i){ int v = bsums[i]; bsums[i] = run; run += v; }
  }
}

__global__ void k_scan3(const int* __restrict__ cnt, const int* __restrict__ bsums,
                        int* __restrict__ rowptr){
  int i = blockIdx.x*blockDim.x + threadIdx.x;
  if (i >= NN) return;
  int incl = rowptr[i];
  int ex = incl - cnt[i] + bsums[i >> 10];
  rowptr[i] = ex;
  if (i == NN-1) rowptr[NN] = ex + cnt[i];
}

__global__ void k_scatter(const int* __restrict__ rows, const int* __restrict__ cols,
                          const int* __restrict__ rowptr, int* __restrict__ tmpc,
                          int* __restrict__ csr){
  int e = blockIdx.x*blockDim.x + threadIdx.x;
  if (e >= EE) return;
  int r = rows[e];
  int p = atomicAdd(&tmpc[r], 1);
  csr[rowptr[r] + p] = cols[e];
}

__global__ void k_degr(const int* __restrict__ cnt, float* __restrict__ r1, float* __restrict__ r2){
  int i = blockIdx.x*blockDim.x + threadIdx.x;
  if (i >= NN) return;
  int d = cnt[i];
  float fd = (float)d;
  r1[i] = (d > 0) ? 1.0f/fd : 1.0f;
  r2[i] = 1.0f/(fd + 1e-5f);
}

// ---------------- propagation: base tensors ----------------
__global__ __launch_bounds__(256) void k_hop1(const float* __restrict__ x,
    const int* __restrict__ rp, const int* __restrict__ cc, float* __restrict__ ax){
  int n = blockIdx.x*4 + (threadIdx.x >> 6);
  int lane = threadIdx.x & 63;
  if (n >= NN) return;
  int s = rp[n], e = rp[n+1];
  float acc = 0.f;
  for (int idx = s; idx < e; ++idx){
    int c = cc[idx];
    acc += x[(size_t)c*64 + lane];
  }
  ax[(size_t)n*64 + lane] = acc;
}

__global__ __launch_bounds__(256) void k_hop2(const int* __restrict__ rp, const int* __restrict__ cc,
    const float* __restrict__ ax, const float* __restrict__ r1, const float* __restrict__ r2,
    float* __restrict__ S0, float* __restrict__ S1, float* __restrict__ S3){
  int n = blockIdx.x*4 + (threadIdx.x >> 6);
  int lane = threadIdx.x & 63;
  if (n >= NN) return;
  int s = rp[n], e = rp[n+1];
  float s0 = 0.f, s1 = 0.f, s3 = 0.f;
  for (int idx = s; idx < e; ++idx){
    int c = cc[idx];
    float v   = ax[(size_t)c*64 + lane];
    float rc1 = r1[c], rc2 = r2[c];
    s0 += v;
    s1 = fmaf(v, rc1, s1);
    s3 = fmaf(v, rc2, s3);
  }
  S0[(size_t)n*64 + lane] = s0;
  S1[(size_t)n*64 + lane] = s1;
  S3[(size_t)n*64 + lane] = s3;
}

// ---------------- Beff build ----------------
__global__ void k_beff(const float* __restrict__ B, float* __restrict__ Beff){
  int gid = blockIdx.x*blockDim.x + threadIdx.x;
  if (gid >= 20*3840) return;
  int p = gid / 3840;
  int rem = gid - p*3840;
  int r = rem / 60, k = rem - (rem/60)*60;
  int t = p >> 2, j = p & 3;
  float val = 0.f;
  if (t == 0)      val = (j == 0) ? B[(0*64 + r)*60 + k] : 0.f;
  else if (t == 1) val = B[((1+j)*64 + r)*60 + k];
  else if (t == 2) val = B[((5+j)*64 + r)*60 + k] + 1.5e-6f*B[((13+j)*64 + r)*60 + k];
  else if (t == 3) val = B[((9+j)*64 + r)*60 + k] + 0.85f  *B[((13+j)*64 + r)*60 + k];
  else             val = B[((17+j)*64 + r)*60 + k];
  Beff[gid] = val;
}

// ---------------- forward ----------------
__global__ __launch_bounds__(256) void k_fwd(
    const float* __restrict__ xi, const float* __restrict__ ax,
    const float* __restrict__ S0, const float* __restrict__ S1,
    const float* __restrict__ S3, const float* __restrict__ Beff,
    const float* __restrict__ r1, const float* __restrict__ r2,
    float* __restrict__ Y){
  __shared__ float As[64][68];   // [k][n] — transposed; pitch 68 keeps 16B alignment
  __shared__ float Bs[64][64];
  __shared__ float cS[4][64];
  const float* Ts[5] = {xi, ax, S0, S1, S3};
  const int pcnt[5] = {1,4,4,4,4};
  int n0 = blockIdx.x*64;
  int tid = threadIdx.x;
  int tx = tid & 15, ty = tid >> 4;
  if (tid < 64){
    int gn = n0 + tid;
    float r1v = 0.f, r2v = 0.f, one = 0.f;
    if (gn < NN){ r1v = r1[gn]; r2v = r2[gn]; one = 1.f; }
    cS[0][tid] = one;
    cS[1][tid] = r1v;
    cS[2][tid] = fmaf(0.85f, r1v, 1.5e-6f*one);
    cS[3][tid] = r2v;
  }
  float acc[4][4] = {};
  for (int t = 0; t < 5; ++t){
    __syncthreads();
    const float* T = Ts[t];
    #pragma unroll
    for (int l = 0; l < 4; ++l){
      int li = tid + l*256;
      int n = li >> 4, fq = (li & 15)*4;
      int gn = n0 + n;
      float4 v = make_float4(0.f,0.f,0.f,0.f);
      if (gn < NN) v = *(const float4*)(T + (size_t)gn*64 + fq);
      As[fq+0][n] = v.x; As[fq+1][n] = v.y; As[fq+2][n] = v.z; As[fq+3][n] = v.w;
    }
    for (int jj = 0; jj < pcnt[t]; ++jj){
      int p = t*4 + jj;
      __syncthreads();
      for (int idx = tid; idx < 64*64; idx += 256){
        int r = idx >> 6, c = idx & 63;
        Bs[r][c] = (c < KK) ? Beff[(size_t)p*3840 + r*60 + c] : 0.f;
      }
      __syncthreads();
      float ptmp[4][4] = {};
      for (int kk = 0; kk < 64; ++kk){
        float4 a = *(const float4*)&As[kk][ty*4];
        float4 b = *(const float4*)&Bs[kk][tx*4];
        ptmp[0][0]=fmaf(a.x,b.x,ptmp[0][0]); ptmp[0][1]=fmaf(a.x,b.y,ptmp[0][1]);
        ptmp[0][2]=fmaf(a.x,b.z,ptmp[0][2]); ptmp[0][3]=fmaf(a.x,b.w,ptmp[0][3]);
        ptmp[1][0]=fmaf(a.y,b.x,ptmp[1][0]); ptmp[1][1]=fmaf(a.y,b.y,ptmp[1][1]);
        ptmp[1][2]=fmaf(a.y,b.z,ptmp[1][2]); ptmp[1][3]=fmaf(a.y,b.w,ptmp[1][3]);
        ptmp[2][0]=fmaf(a.z,b.x,ptmp[2][0]); ptmp[2][1]=fmaf(a.z,b.y,ptmp[2][1]);
        ptmp[2][2]=fmaf(a.z,b.z,ptmp[2][2]); ptmp[2][3]=fmaf(a.z,b.w,ptmp[2][3]);
        ptmp[3][0]=fmaf(a.w,b.x,ptmp[3][0]); ptmp[3][1]=fmaf(a.w,b.y,ptmp[3][1]);
        ptmp[3][2]=fmaf(a.w,b.z,ptmp[3][2]); ptmp[3][3]=fmaf(a.w,b.w,ptmp[3][3]);
      }
      #pragma unroll
      for (int i = 0; i < 4; ++i){
        float cv = cS[jj][ty*4+i];
        #pragma unroll
        for (int q = 0; q < 4; ++q) acc[i][q] = fmaf(cv, ptmp[i][q], acc[i][q]);
      }
    }
  }
  #pragma unroll
  for (int i = 0; i < 4; ++i){
    int gn = n0 + ty*4 + i;
    if (gn >= NN) continue;
    #pragma unroll
    for (int q = 0; q < 4; ++q){
      int c = tx*4 + q;
      if (c < KK) Y[(size_t)gn*KK + c] = acc[i][q];
    }
  }
}

// ---------------- backward partials ----------------
__device__ __forceinline__ void fma44(const float4 a, const float4 b, float (&acc)[4][4]){
  acc[0][0] = fmaf(a.x,b.x,acc[0][0]); acc[0][1] = fmaf(a.x,b.y,acc[0][1]);
  acc[0][2] = fmaf(a.x,b.z,acc[0][2]); acc[0][3] = fmaf(a.x,b.w,acc[0][3]);
  acc[1][0] = fmaf(a.y,b.x,acc[1][0]); acc[1][1] = fmaf(a.y,b.y,acc[1][1]);
  acc[1][2] = fmaf(a.y,b.z,acc[1][2]); acc[1][3] = fmaf(a.y,b.w,acc[1][3]);
  acc[2][0] = fmaf(a.z,b.x,acc[2][0]); acc[2][1] = fmaf(a.z,b.y,acc[2][1]);
  acc[2][2] = fmaf(a.z,b.z,acc[2][2]); acc[2][3] = fmaf(a.z,b.w,acc[2][3]);
  acc[3][0] = fmaf(a.w,b.x,acc[3][0]); acc[3][1] = fmaf(a.w,b.y,acc[3][1]);
  acc[3][2] = fmaf(a.w,b.z,acc[3][2]); acc[3][3] = fmaf(a.w,b.w,acc[3][3]);
}

__global__ __launch_bounds__(256) void k_bwd(
    const float* __restrict__ xi, const float* __restrict__ ax,
    const float* __restrict__ S0t, const float* __restrict__ S1t,
    const float* __restrict__ S3t, const float* __restrict__ Qm,
    const float* __restrict__ r1, const float* __restrict__ r2,
    float* __restrict__ Ppart){
  const float* T = (blockIdx.x==0)?xi:(blockIdx.x==1)?ax:(blockIdx.x==2)?S0t:(blockIdx.x==3)?S1t:S3t;
  const int TT = (NN + 15)/16;
  int per = (TT + BSPLIT - 1)/BSPLIT;
  int t0 = blockIdx.y * per;
  int t1 = t0 + per; if (t1 > TT) t1 = TT;
  __shared__ float Hs[16][68];
  __shared__ float Qs[16][64];
  __shared__ float cs[4][16];
  int tid = threadIdx.x, tx = tid & 15, ty = tid >> 4;
  float acc[4][4][4] = {};
  for (int tl = t0; tl < t1; ++tl){
    int nb = tl*16;
    {
      int n = tid >> 4, fq = (tid & 15)*4;
      int gn = nb + n;
      float4 v = make_float4(0.f,0.f,0.f,0.f);
      if (gn < NN) v = *(const float4*)(T + (size_t)gn*64 + fq);
      *(float4*)&Hs[n][fq] = v;
    }
    if (tid < 240){
      int n = tid/15, cq = (tid - (tid/15)*15)*4;
      int gn = nb + n;
      float4 v = make_float4(0.f,0.f,0.f,0.f);
      if (gn < NN) v = *(const float4*)(Qm + (size_t)gn*KK + cq);
      *(float4*)&Qs[n][cq] = v;
    } else {
      int n = tid - 240;
      Qs[n][60]=0.f; Qs[n][61]=0.f; Qs[n][62]=0.f; Qs[n][63]=0.f;
    }
    if (tid < 64){
      int j = tid >> 4, n = tid & 15;
      int gn = nb + n;
      float r1v = 0.f, r2v = 0.f, one = 0.f;
      if (gn < NN){ r1v = r1[gn]; r2v = r2[gn]; one = 1.f; }
      cs[j][n] = (j==0) ? one : (j==1) ? r1v : (j==2) ? fmaf(0.85f, r1v, 1.5e-6f*one) : r2v;
    }
    __syncthreads();
    #pragma unroll 4
    for (int n = 0; n < 16; ++n){
      float4 a = *(const float4*)&Hs[n][tx*4];
      float4 b = *(const float4*)&Qs[n][ty*4];
      #pragma unroll
      for (int j = 0; j < 4; ++j){
        float cj = cs[j][n];
        float4 bj = make_float4(b.x*cj, b.y*cj, b.z*cj, b.w*cj);
        fma44(a, bj, acc[j]);
      }
    }
    __syncthreads();
  }
  float* dst = Ppart + (size_t)blockIdx.y * 76800;
  #pragma unroll
  for (int j = 0; j < 4; ++j){
    #pragma unroll
    for (int i = 0; i < 4; ++i){
      int f = tx*4 + i;
      #pragma unroll
      for (int q = 0; q < 4; ++q){
        int k = ty*4 + q;
        if (k < KK) dst[(size_t)((blockIdx.x*4 + j)*64 + f)*60 + k] = acc[j][i][q];
      }
    }
  }
}

__global__ void k_pred(const float* __restrict__ Ppart, float* __restrict__ P){
  int gid = blockIdx.x*blockDim.x + threadIdx.x;
  if (gid >= 20*3840) return;
  float s = 0.f;
  for (int b = 0; b < BSPLIT; ++b) s += Ppart[(size_t)b*76800 + gid];
  P[gid] = s;
}

__global__ void k_zasm(const float* __restrict__ P, float* __restrict__ Z){
  int gid = blockIdx.x*blockDim.x + threadIdx.x;
  if (gid >= FF*KK) return;
  int f = gid / 60, k = gid - (gid/60)*60;
  int b = f >> 6, fi = f & 63;
  float val;
  if (b == 0)       val = P[(size_t)((0*4+0)*64 + fi)*60 + k];
  else if (b < 5)   val = P[(size_t)((1*4 + (b-1))*64 + fi)*60 + k];
  else if (b < 9)   val = P[(size_t)((2*4 + (b-5))*64 + fi)*60 + k];
  else if (b < 13)  val = P[(size_t)((3*4 + (b-9))*64 + fi)*60 + k];
  else if (b < 17)  val = 0.85f  *P[(size_t)((3*4 + (b-13))*64 + fi)*60 + k]
                        + 1.5e-6f*P[(size_t)((2*4 + (b-13))*64 + fi)*60 + k];
  else              val = P[(size_t)((4*4 + (b-17))*64 + fi)*60 + k];
  Z[gid] = val;
}

// ---------------- CholQR pieces ----------------
__global__ __launch_bounds__(256) void k_syrk(const float* __restrict__ X, int nrows,
                                              float* __restrict__ Cout){
  int chunk = (nrows + gridDim.x - 1) / gridDim.x;
  int nb = blockIdx.x * chunk;
  int ne = nb + chunk; if (ne > nrows) ne = nrows;
  __shared__ float Xs[16][64];
  int tid = threadIdx.x;
  int tx = tid & 15, ty = tid >> 4;
  float acc[4][4] = {};
  for (int nbase = nb; nbase < ne; nbase += 16){
    if (tid < 240){
      int n = tid / 15, ci = tid - (tid/15)*15;
      float4 v = make_float4(0.f,0.f,0.f,0.f);
      int gn = nbase + n;
      if (gn < ne) v = *(const float4*)(X + (size_t)gn*KK + ci*4);
      *(float4*)&Xs[n][ci*4] = v;
    } else {
      int n = tid - 240;
      Xs[n][60]=0.f; Xs[n][61]=0.f; Xs[n][62]=0.f; Xs[n][63]=0.f;
    }
    __syncthreads();
    #pragma unroll
    for (int n = 0; n < 16; ++n){
      float4 a = *(const float4*)&Xs[n][tx*4];
      float4 b = *(const float4*)&Xs[n][ty*4];
      fma44(a, b, acc);
    }
    __syncthreads();
  }
  #pragma unroll
  for (int i = 0; i < 4; ++i){
    int r = tx*4 + i;
    #pragma unroll
    for (int j = 0; j < 4; ++j){
      int c = ty*4 + j;
      if (r < KK && c < KK) atomicAdd(&Cout[r*KK + c], acc[i][j]);
    }
  }
}

// Cholesky (upper) + blocked triangular inverse. 256 threads.
__global__ __launch_bounds__(256) void k_cholinv(const float* __restrict__ Cin,
                                                 float* __restrict__ Rinv){
  __shared__ float R[60][65];
  __shared__ float Ri[60][65];
  __shared__ float Tmp[30][33];
  __shared__ float ridge;
  int t = threadIdx.x;
  for (int i = t; i < 3840; i += 256){
    int r = i >> 6, c = i & 63;
    if (c < 60) R[r][c] = Cin[r*60 + c];
  }
  __syncthreads();
  if (t == 0){
    float tr = 0.f;
    for (int i = 0; i < 60; ++i) tr += R[i][i];
    ridge = 1e-7f*(tr/60.f) + 1e-30f;
  }
  __syncthreads();
  if (t < 60) R[t][t] += ridge;
  __syncthreads();
  for (int j = 0; j < 60; ++j){
    if (t == 0) R[j][j] = sqrtf(fmaxf(R[j][j], 1e-30f));
    __syncthreads();
    float rjj = R[j][j];
    for (int i = j+1+t; i < 60; i += 256) R[j][i] /= rjj;
    __syncthreads();
    int nrow = 59 - j;
    for (int task = t; task < nrow*64; task += 256){
      int k = j + 1 + (task >> 6), i = task & 63;
      if (i >= k && i < 60) R[k][i] -= R[j][k]*R[j][i];
    }
    __syncthreads();
  }
  for (int i = t; i < 3840; i += 256){ int r = i >> 6, c = i & 63; Ri[r][c] = 0.f; }
  __syncthreads();
  // invert the two 30x30 diagonal blocks, column per thread
  if (t < 60){
    int c = t;
    int lo = (c < 30) ? 0 : 30;
    Ri[c][c] = 1.0f / R[c][c];
    for (int i = c-1; i >= lo; --i){
      float s = 0.f;
      for (int k = i+1; k <= c; ++k) s += R[i][k]*Ri[k][c];
      Ri[i][c] = -s / R[i][i];
    }
  }
  __syncthreads();
  // Tmp = R12 * Ri22
  for (int idx2 = t; idx2 < 960; idx2 += 256){
    int r = idx2 >> 5, c = idx2 & 31;
    if (c < 30){
      float s = 0.f;
      for (int k = 0; k <= c; ++k) s += R[r][30+k]*Ri[30+k][30+c];
      Tmp[r][c] = s;
    }
  }
  __syncthreads();
  // Ri12 = -Ri11 * Tmp
  for (int idx2 = t; idx2 < 960; idx2 += 256){
    int r = idx2 >> 5, c = idx2 & 31;
    if (c < 30){
      float s = 0.f;
      for (int k = r; k < 30; ++k) s += Ri[r][k]*Tmp[k][c];
      Ri[r][30+c] = -s;
    }
  }
  __syncthreads();
  for (int i = t; i < 3600; i += 256) Rinv[i] = Ri[i/60][i%60];
}

// X = Y @ Rinv — 16 rows per block, in-place safe (wave owns its rows)
__global__ __launch_bounds__(256) void k_applyR(const float* Yin,
    const float* __restrict__ Rinv, float* Xout, int nrows){
  __shared__ float Rs[3600];
  for (int i = threadIdx.x; i < 3600; i += 256) Rs[i] = Rinv[i];
  __syncthreads();
  int w = threadIdx.x >> 6, lane = threadIdx.x & 63;
  #pragma unroll
  for (int r = 0; r < 4; ++r){
    int n = blockIdx.x*16 + w*4 + r;
    if (n >= nrows) continue;
    const float* y = Yin + (size_t)n*KK;
    float accv = 0.f;
    #pragma unroll 10
    for (int k2 = 0; k2 < KK; ++k2) accv = fmaf(y[k2], Rs[k2*KK + lane], accv);
    if (lane < KK) Xout[(size_t)n*KK + lane] = accv;
  }
}

// WB[60x64] = Z^T @ w
__global__ void k_wb(const float* __restrict__ Z, const float* __restrict__ w,
                     float* __restrict__ WB){
  int gid = blockIdx.x*blockDim.x + threadIdx.x;
  if (gid >= KK*64) return;
  int r = gid >> 6, d = gid & 63;
  float acc = 0.f;
  for (int f = 0; f < FF; ++f) acc = fmaf(Z[(size_t)f*KK + r], w[(size_t)f*64 + d], acc);
  WB[gid] = acc;
}

// Jacobi eigensolver, 512 threads, padded indexing, pitch 65 (conflict-free columns)
__global__ __launch_bounds__(512) void k_jacobi(const float* __restrict__ Min,
                                                float* __restrict__ U50){
  __shared__ float A[60][65];
  __shared__ float Vv[60][65];
  __shared__ float cs[32], sn[32];
  __shared__ int pp[32], qq[32];
  __shared__ float ev[64];
  __shared__ int idx[64];
  int t = threadIdx.x;
  for (int i = t; i < 3840; i += 512){
    int r = i >> 6, c = i & 63;
    if (c < 60){ A[r][c] = Min[r*60 + c]; Vv[r][c] = (r == c) ? 1.f : 0.f; }
  }
  __syncthreads();
  for (int sweep = 0; sweep < 8; ++sweep){
    for (int round = 0; round < 59; ++round){
      if (t < 30){
        int i = t, j2 = 59 - t;
        int p = (i == 0) ? 0 : ((i - 1 + round) % 59 + 1);
        int q = ((j2 - 1 + round) % 59 + 1);
        if (p > q){ int tv = p; p = q; q = tv; }
        pp[t] = p; qq[t] = q;
        float app = A[p][p], aqq = A[q][q], apq = A[p][q];
        float c, s;
        if (fabsf(apq) < 1e-36f){ c = 1.f; s = 0.f; }
        else {
          float tau = (aqq - app) / (2.f * apq);
          float tt = ((tau >= 0.f) ? 1.f : -1.f) / (fabsf(tau) + sqrtf(1.f + tau*tau));
          c = 1.f / sqrtf(1.f + tt*tt);
          s = tt * c;
        }
        cs[t] = c; sn[t] = s;
      }
      __syncthreads();
      for (int task = t; task < 1920; task += 512){
        int k = task >> 6, i = task & 63;
        if (i < 60){
          int p = pp[k], q = qq[k];
          float c = cs[k], s = sn[k];
          float aip = A[i][p], aiq = A[i][q];
          A[i][p] = c*aip - s*aiq;  A[i][q] = s*aip + c*aiq;
          float vip = Vv[i][p], viq = Vv[i][q];
          Vv[i][p] = c*vip - s*viq; Vv[i][q] = s*vip + c*viq;
        }
      }
      __syncthreads();
      for (int task = t; task < 1920; task += 512){
        int k = task >> 6, i = task & 63;
        if (i < 60){
          int p = pp[k], q = qq[k];
          float c = cs[k], s = sn[k];
          float api = A[p][i], aqi = A[q][i];
          A[p][i] = c*api - s*aqi;  A[q][i] = s*api + c*aqi;
        }
      }
      __syncthreads();
    }
  }
  if (t < 60) ev[t] = A[t][t];
  __syncthreads();
  if (t < 60){
    float mine = ev[t];
    int rank = 0;
    for (int j = 0; j < 60; ++j){
      float o = ev[j];
      if (o > mine || (o == mine && j < t)) ++rank;
    }
    if (rank < RK) idx[rank] = t;
  }
  __syncthreads();
  for (int i2 = t; i2 < 60*RK; i2 += 512){
    int r = i2 / RK, c = i2 - (i2/RK)*RK;
    U50[i2] = Vv[r][idx[c]];
  }
}

__global__ void k_g50(const float* __restrict__ U50, const float* __restrict__ WB,
                      float* __restrict__ G50){
  int gid = blockIdx.x*blockDim.x + threadIdx.x;
  if (gid >= RK*64) return;
  int r = gid >> 6, d = gid & 63;
  float acc = 0.f;
  for (int i = 0; i < KK; ++i) acc = fmaf(U50[i*RK + r], WB[i*64 + d], acc);
  G50[gid] = acc;
}

__global__ void k_T(const float* __restrict__ U50, const float* __restrict__ G50,
                    float* __restrict__ Tm){
  int gid = blockIdx.x*blockDim.x + threadIdx.x;
  if (gid >= KK*64) return;
  int i = gid >> 6, d = gid & 63;
  float acc = 0.f;
  for (int r = 0; r < RK; ++r) acc = fmaf(U50[i*RK + r], G50[r*64 + d], acc);
  Tm[gid] = acc;
}

__global__ void k_TW1(const float* __restrict__ Tm, const float* __restrict__ W1,
                      float* __restrict__ TW1){
  int gid = blockIdx.x*blockDim.x + threadIdx.x;
  if (gid >= KK*HIDN) return;
  int i = gid >> 5, j = gid & 31;
  float acc = 0.f;
  for (int d = 0; d < 64; ++d) acc = fmaf(Tm[i*64 + d], W1[d*HIDN + j], acc);
  TW1[gid] = acc;
}

__global__ __launch_bounds__(256) void k_hid(const float* __restrict__ Q,
    const float* __restrict__ TW1, const float* __restrict__ b1, float* __restrict__ hid){
  __shared__ float Ts[KK*HIDN];
  __shared__ float bs[HIDN];
  for (int i = threadIdx.x; i < KK*HIDN; i += 256) Ts[i] = TW1[i];
  if (threadIdx.x < HIDN) bs[threadIdx.x] = b1[threadIdx.x];
  __syncthreads();
  int gid = blockIdx.x*256 + threadIdx.x;
  if (gid >= NN*HIDN) return;
  int n = gid >> 5, j = gid & 31;
  const float* q = Q + (size_t)n*KK;
  float a = bs[j];
  #pragma unroll 10
  for (int k2 = 0; k2 < KK; ++k2) a = fmaf(q[k2], Ts[k2*HIDN + j], a);
  hid[gid] = (a >= 0.f) ? a : 0.01f*a;
}

__global__ void k_gstart(const int* __restrict__ gids, int* __restrict__ gst){
  int g = blockIdx.x*blockDim.x + threadIdx.x;
  if (g > GG) return;
  if (g == GG){ gst[GG] = NN; return; }
  int lo = 0, hi = NN;
  while (lo < hi){ int mid = (lo + hi) >> 1; if (gids[mid] < g) lo = mid + 1; else hi = mid; }
  gst[g] = lo;
}

__global__ __launch_bounds__(256) void k_pool(const float* __restrict__ hid,
    const float* __restrict__ W2, const int* __restrict__ gst, float* __restrict__ out){
  int g = blockIdx.x, ct = blockIdx.y;
  int c0 = ct * 64;
  __shared__ float W2s[HIDN][64];
  __shared__ float part[4][64];
  for (int i = threadIdx.x; i < HIDN*64; i += 256){
    int k2 = i >> 6, c = i & 63;
    int col = c0 + c;
    W2s[k2][c] = (col < NCL) ? W2[(size_t)k2*NCL + col] : 0.f;
  }
  __syncthreads();
  int w = threadIdx.x >> 6, lane = threadIdx.x & 63;
  int s = gst[g], e = gst[g+1];
  float accv = 0.f;
  for (int n = s + w; n < e; n += 4){
    const float* hr = hid + (size_t)n*HIDN;
    #pragma unroll
    for (int k2 = 0; k2 < HIDN; ++k2) accv = fmaf(hr[k2], W2s[k2][lane], accv);
  }
  part[w][lane] = accv;
  __syncthreads();
  if (w == 0){
    float v = part[0][lane] + part[1][lane] + part[2][lane] + part[3][lane];
    int col = c0 + lane;
    if (col < NCL) out[(size_t)g*NCL + col] = v;
  }
}

// ---------------- host ----------------
extern "C" void kernel_launch(void* const* d_in, const int* in_sizes, int n_in,
                              void* d_out, int out_size, void* d_ws, size_t ws_size,
                              hipStream_t stream){
  (void)in_sizes; (void)n_in; (void)out_size;
  const float* x   = (const float*)d_in[0];
  const int*  rows = (const int*)d_in[1];
  const int*  cols = (const int*)d_in[2];
  const int*  gids = (const int*)d_in[3];
  const float* wM  = (const float*)d_in[5];
  const float* W1  = (const float*)d_in[6];
  const float* b1  = (const float*)d_in[7];
  const float* W2  = (const float*)d_in[8];
  float* out = (float*)d_out;

  char* base = (char*)d_ws;
  size_t off = 0;
  auto alloc = [&](size_t bytes)->char*{
    off = (off + 255) & ~(size_t)255;
    char* p = base + off; off += bytes; return p;
  };
  float* ax    = (float*)alloc((size_t)NN*64*4);   // later reused as hid
  float* S0    = (float*)alloc((size_t)NN*64*4);
  float* S1    = (float*)alloc((size_t)NN*64*4);
  float* S3    = (float*)alloc((size_t)NN*64*4);
  float* Y     = (float*)alloc((size_t)NN*KK*4);   // becomes Q in place
  int*   csr   = (int*)  alloc((size_t)EE*4);
  float* Ppart = (float*)alloc((size_t)BSPLIT*20*3840*4);
  float* Psum  = (float*)alloc((size_t)20*3840*4);
  float* Beff  = (float*)alloc((size_t)20*3840*4);
  float* Om    = (float*)alloc((size_t)FF*KK*4);
  float* Zf    = (float*)alloc((size_t)FF*KK*4);
  float* Cm    = (float*)alloc(3600*4);
  float* Rinv  = (float*)alloc(3600*4);
  float* Mm    = (float*)alloc(3600*4);
  float* U50   = (float*)alloc(60*RK*4);
  float* WB    = (float*)alloc(KK*64*4);
  float* G50   = (float*)alloc(RK*64*4);
  float* Tm    = (float*)alloc(KK*64*4);
  float* TW1   = (float*)alloc(KK*HIDN*4);
  float* r1    = (float*)alloc((size_t)NN*4);
  float* r2    = (float*)alloc((size_t)NN*4);
  int* cnt     = (int*)alloc((size_t)NN*4);
  int* rowptr  = (int*)alloc((size_t)(NN+1)*4);
  int* tmpc    = (int*)alloc((size_t)NN*4);
  int* gst     = (int*)alloc((size_t)(GG+1)*4);
  int* bsums   = (int*)alloc(256*4);
  float* hid   = ax;  // overlay: ax dead after final k_bwd
  if (off > ws_size) return;

  const int SCAN_B = (NN + 1023) / 1024;

  // ---- graph prep ----
  hipMemsetAsync(cnt, 0, (size_t)NN*4, stream);
  k_count<<<(EE+255)/256, 256, 0, stream>>>(rows, cnt);
  k_scan1<<<SCAN_B, 1024, 0, stream>>>(cnt, rowptr, bsums);
  k_scan2<<<1, 64, 0, stream>>>(bsums, SCAN_B);
  k_scan3<<<(NN+255)/256, 256, 0, stream>>>(cnt, bsums, rowptr);
  hipMemsetAsync(tmpc, 0, (size_t)NN*4, stream);
  k_scatter<<<(EE+255)/256, 256, 0, stream>>>(rows, cols, rowptr, tmpc, csr);
  k_degr<<<(NN+255)/256, 256, 0, stream>>>(cnt, r1, r2);

  // ---- base tensors ----
  k_hop1<<<(NN+3)/4, 256, 0, stream>>>(x, rowptr, csr, ax);
  k_hop2<<<(NN+3)/4, 256, 0, stream>>>(rowptr, csr, ax, r1, r2, S0, S1, S3);

  // ---- omega ----
  k_omega<<<(FF*KK+255)/256, 256, 0, stream>>>(Om);

  auto gramR = [&](float* Xbuf, int nrows, int grid){   // Cm=X^T X, Rinv=chol^{-1}
    hipMemsetAsync(Cm, 0, 3600*4, stream);
    k_syrk<<<grid, 256, 0, stream>>>(Xbuf, nrows, Cm);
    k_cholinv<<<1, 256, 0, stream>>>(Cm, Rinv);
  };
  auto bwd = [&](const float* Qbuf){
    k_bwd<<<dim3(5, BSPLIT), 256, 0, stream>>>(x, ax, S0, S1, S3, Qbuf, r1, r2, Ppart);
    k_pred<<<(20*3840+255)/256, 256, 0, stream>>>(Ppart, Psum);
    k_zasm<<<(FF*KK+255)/256, 256, 0, stream>>>(Psum, Zf);
  };
  auto fwd = [&](const float* Bmat){
    k_beff<<<(20*3840+255)/256, 256, 0, stream>>>(Bmat, Beff);
    k_fwd<<<(NN+63)/64, 256, 0, stream>>>(x, ax, S0, S1, S3, Beff, r1, r2, Y);
  };

  // ---- Y0 = h @ omega ----
  fwd(Om);

  // ---- power iterations (Rinv of the N-side QR deferred to the F side) ----
  for (int it = 0; it < 4; ++it){
    gramR(Y, NN, 256);                                   // R_N from Y
    bwd(Y);                                              // Zf = h^T Y
    k_applyR<<<(FF+15)/16, 256, 0, stream>>>(Zf, Rinv, Zf, FF);   // Zf = h^T Q
    gramR(Zf, FF, 32);                                   // F-side QR
    k_applyR<<<(FF+15)/16, 256, 0, stream>>>(Zf, Rinv, Zf, FF);   // Qf
    fwd(Zf);                                             // Y = h Qf
  }

  // ---- final Q: CholQR2 ----
  gramR(Y, NN, 256);
  k_applyR<<<(NN+15)/16, 256, 0, stream>>>(Y, Rinv, Y, NN);
  gramR(Y, NN, 256);
  k_applyR<<<(NN+15)/16, 256, 0, stream>>>(Y, Rinv, Y, NN);

  // ---- B-side smalls ----
  bwd(Y);                                                // Zf = h^T Q (Q orthonormal)
  hipMemsetAsync(Mm, 0, 3600*4, stream);
  k_syrk<<<32, 256, 0, stream>>>(Zf, FF, Mm);
  k_wb<<<(KK*64+255)/256, 256, 0, stream>>>(Zf, wM, WB);

  // ---- eigensolve + projector chain ----
  k_jacobi<<<1, 512, 0, stream>>>(Mm, U50);
  k_g50<<<(RK*64+255)/256, 256, 0, stream>>>(U50, WB, G50);
  k_T<<<(KK*64+255)/256, 256, 0, stream>>>(U50, G50, Tm);
  k_TW1<<<(KK*HIDN+255)/256, 256, 0, stream>>>(Tm, W1, TW1);

  // ---- MLP + pooling (hid overlays ax) ----
  k_hid<<<(NN*HIDN+255)/256, 256, 0, stream>>>(Y, TW1, b1, hid);
  k_gstart<<<1, 256, 0, stream>>>(gids, gst);
  k_pool<<<dim3(GG, (NCL+63)/64), 256, 0, stream>>>(hid, W2, gst, out);
}